// Round 1
// baseline (60.994 us; speedup 1.0000x reference)
//
#include <hip/hip_runtime.h>
#include <math.h>

// DescriptorBuilder: radial (k=0..8 powers * cosine cutoff) + angular
// (Legendre P0..P2 x (rij*rik)^n, n=0..2) descriptors, N=192 atoms, MIC PBC.
//
// Key algebraic reduction: the O(N^3) angular triple sum is separable per
// center i using moment accumulation:
//   l=0: (sum_j w)^2
//   l=1: |sum_j w*u|^2                  (u = dr/r unit vector)
//   l=2: 1.5*|sum_j w*u u^T|_F^2 - 0.5*(sum_j w)^2
// with w = fc(r)*r^n. This makes the whole kernel one O(N^2) pair loop.

namespace {

constexpr float RC_   = 6.0f;
constexpr float PI_F  = 3.14159265358979323846f;

__global__ __launch_bounds__(64)
void desc_kernel(const float* __restrict__ R,
                 const float* __restrict__ box,
                 float* __restrict__ out,
                 int N)
{
    const int i    = blockIdx.x;
    const int lane = threadIdx.x;

    // ---- box and its inverse (9 floats, computed redundantly per thread) ----
    const float b00 = box[0], b01 = box[1], b02 = box[2];
    const float b10 = box[3], b11 = box[4], b12 = box[5];
    const float b20 = box[6], b21 = box[7], b22 = box[8];
    const float c00 =  (b11 * b22 - b12 * b21);
    const float c10 = -(b10 * b22 - b12 * b20);
    const float c20 =  (b10 * b21 - b11 * b20);
    const float det = b00 * c00 + b01 * c10 + b02 * c20;
    const float id  = 1.0f / det;
    const float i00 = c00 * id;
    const float i01 = (b02 * b21 - b01 * b22) * id;
    const float i02 = (b01 * b12 - b02 * b11) * id;
    const float i10 = c10 * id;
    const float i11 = (b00 * b22 - b02 * b20) * id;
    const float i12 = (b02 * b10 - b00 * b12) * id;
    const float i20 = c20 * id;
    const float i21 = (b01 * b20 - b00 * b21) * id;
    const float i22 = (b00 * b11 - b01 * b10) * id;

    // ---- center atom fractional coords ----
    const float Rix = R[3 * i + 0], Riy = R[3 * i + 1], Riz = R[3 * i + 2];
    const float six = i00 * Rix + i01 * Riy + i02 * Riz;
    const float siy = i10 * Rix + i11 * Riy + i12 * Riz;
    const float siz = i20 * Rix + i21 * Riy + i22 * Riz;

    // ---- per-lane accumulators: 9 radial + 3n x (1 S + 3 V + 6 M) = 39 ----
    float qr[9];
#pragma unroll
    for (int k = 0; k < 9; ++k) qr[k] = 0.0f;
    float S[3] = {0.0f, 0.0f, 0.0f};
    float V[3][3];
    float M[3][6];
#pragma unroll
    for (int n = 0; n < 3; ++n) {
#pragma unroll
        for (int c = 0; c < 3; ++c) V[n][c] = 0.0f;
#pragma unroll
        for (int c = 0; c < 6; ++c) M[n][c] = 0.0f;
    }

    for (int j = lane; j < N; j += 64) {
        if (j == i) continue;
        const float Rjx = R[3 * j + 0], Rjy = R[3 * j + 1], Rjz = R[3 * j + 2];
        const float sjx = i00 * Rjx + i01 * Rjy + i02 * Rjz;
        const float sjy = i10 * Rjx + i11 * Rjy + i12 * Rjz;
        const float sjz = i20 * Rjx + i21 * Rjy + i22 * Rjz;
        // minimum image in fractional space (jnp.round == rint, half-to-even)
        float dsx = six - sjx; dsx -= rintf(dsx);
        float dsy = siy - sjy; dsy -= rintf(dsy);
        float dsz = siz - sjz; dsz -= rintf(dsz);
        const float dx = b00 * dsx + b01 * dsy + b02 * dsz;
        const float dy = b10 * dsx + b11 * dsy + b12 * dsz;
        const float dz = b20 * dsx + b21 * dsy + b22 * dsz;
        const float r2 = dx * dx + dy * dy + dz * dz;
        const float r  = sqrtf(r2);
        if (r >= RC_) continue;   // fc == 0 beyond cutoff (clip->cos(pi)->0)

        const float fc = 0.5f * (cosf(PI_F * (r * (1.0f / RC_))) + 1.0f);

        // radial: q_r[k] += r^k * fc
        float rp = 1.0f;
#pragma unroll
        for (int k = 0; k < 9; ++k) { qr[k] += rp * fc; rp *= r; }

        // angular moments: w_n = fc * r^n, unit vector u
        const float ir = 1.0f / r;
        const float ux = dx * ir, uy = dy * ir, uz = dz * ir;
        float w = fc;
#pragma unroll
        for (int n = 0; n < 3; ++n) {
            S[n]    += w;
            V[n][0] += w * ux;      V[n][1] += w * uy;      V[n][2] += w * uz;
            M[n][0] += w * ux * ux; M[n][1] += w * uy * uy; M[n][2] += w * uz * uz;
            M[n][3] += w * ux * uy; M[n][4] += w * ux * uz; M[n][5] += w * uy * uz;
            w *= r;
        }
    }

    // ---- wave-wide butterfly reduction over 64 lanes ----
#pragma unroll
    for (int off = 32; off > 0; off >>= 1) {
#pragma unroll
        for (int k = 0; k < 9; ++k) qr[k] += __shfl_xor(qr[k], off);
#pragma unroll
        for (int n = 0; n < 3; ++n) {
            S[n] += __shfl_xor(S[n], off);
#pragma unroll
            for (int c = 0; c < 3; ++c) V[n][c] += __shfl_xor(V[n][c], off);
#pragma unroll
            for (int c = 0; c < 6; ++c) M[n][c] += __shfl_xor(M[n][c], off);
        }
    }

    if (lane == 0) {
        float* o = out + i * 18;
#pragma unroll
        for (int k = 0; k < 9; ++k) o[k] = qr[k];
#pragma unroll
        for (int n = 0; n < 3; ++n) {
            const float s  = S[n];
            const float v2 = V[n][0] * V[n][0] + V[n][1] * V[n][1] + V[n][2] * V[n][2];
            const float m2 = M[n][0] * M[n][0] + M[n][1] * M[n][1] + M[n][2] * M[n][2]
                     + 2.0f * (M[n][3] * M[n][3] + M[n][4] * M[n][4] + M[n][5] * M[n][5]);
            o[9 + n * 3 + 0] = s * s;                  // P0 term
            o[9 + n * 3 + 1] = v2;                     // P1 term
            o[9 + n * 3 + 2] = 1.5f * m2 - 0.5f * s * s; // P2 term
        }
    }
}

} // namespace

extern "C" void kernel_launch(void* const* d_in, const int* in_sizes, int n_in,
                              void* d_out, int out_size, void* d_ws, size_t ws_size,
                              hipStream_t stream)
{
    const float* R   = (const float*)d_in[0];   // [N,3] float32
    // d_in[1] = Z (int32) — unused by the reference computation
    const float* box = (const float*)d_in[2];   // [3,3] float32
    float* out = (float*)d_out;                 // [N,18] float32
    const int N = in_sizes[0] / 3;

    desc_kernel<<<dim3(N), dim3(64), 0, stream>>>(R, box, out, N);
}

// Round 2
// 60.369 us; speedup vs baseline: 1.0104x; 1.0104x over previous
//
#include <hip/hip_runtime.h>
#include <math.h>

// DescriptorBuilder: radial (k=0..8 powers * cosine cutoff) + angular
// (Legendre P0..P2 x (rij*rik)^n, n=0..2) descriptors, N=192 atoms, MIC PBC.
//
// O(N^3) angular triple sum is separable per center i via moments:
//   l=0: S^2,  l=1: |V|^2,  l=2: 1.5*|M|_F^2 - 0.5*S^2
// with w = fc(r)*r^n, S=sum w, V=sum w*u, M=sum w*u u^T (u=dr/r).
// Note S[n] == q_r[n] (identical arithmetic) -> not accumulated separately.
// One O(N^2) pair loop: grid=N blocks x 1 wave; butterfly reduce 36 floats.

namespace {

constexpr float RC_  = 6.0f;
constexpr float PI_F = 3.14159265358979323846f;

__global__ __launch_bounds__(64)
void desc_kernel(const float* __restrict__ R,
                 const float* __restrict__ box,
                 float* __restrict__ out,
                 int N)
{
    const int i    = blockIdx.x;
    const int lane = threadIdx.x;

    // ---- box and its inverse (computed redundantly per thread; 9 floats) ----
    const float b00 = box[0], b01 = box[1], b02 = box[2];
    const float b10 = box[3], b11 = box[4], b12 = box[5];
    const float b20 = box[6], b21 = box[7], b22 = box[8];
    const float c00 =  (b11 * b22 - b12 * b21);
    const float c10 = -(b10 * b22 - b12 * b20);
    const float c20 =  (b10 * b21 - b11 * b20);
    const float det = b00 * c00 + b01 * c10 + b02 * c20;
    const float id  = 1.0f / det;
    const float i00 = c00 * id;
    const float i01 = (b02 * b21 - b01 * b22) * id;
    const float i02 = (b01 * b12 - b02 * b11) * id;
    const float i10 = c10 * id;
    const float i11 = (b00 * b22 - b02 * b20) * id;
    const float i12 = (b02 * b10 - b00 * b12) * id;
    const float i20 = c20 * id;
    const float i21 = (b01 * b20 - b00 * b21) * id;
    const float i22 = (b00 * b11 - b01 * b10) * id;

    // ---- center atom fractional coords ----
    const float Rix = R[3 * i + 0], Riy = R[3 * i + 1], Riz = R[3 * i + 2];
    const float six = i00 * Rix + i01 * Riy + i02 * Riz;
    const float siy = i10 * Rix + i11 *Riy + i12 * Riz;
    const float siz = i20 * Rix + i21 * Riy + i22 * Riz;

    // ---- per-lane accumulators: 9 radial (qr[0..2] double as S) + 3x(3V+6M) ----
    float qr[9];
#pragma unroll
    for (int k = 0; k < 9; ++k) qr[k] = 0.0f;
    float V[3][3];
    float M[3][6];
#pragma unroll
    for (int n = 0; n < 3; ++n) {
#pragma unroll
        for (int c = 0; c < 3; ++c) V[n][c] = 0.0f;
#pragma unroll
        for (int c = 0; c < 6; ++c) M[n][c] = 0.0f;
    }

    for (int j = lane; j < N; j += 64) {
        if (j == i) continue;
        const float Rjx = R[3 * j + 0], Rjy = R[3 * j + 1], Rjz = R[3 * j + 2];
        const float sjx = i00 * Rjx + i01 * Rjy + i02 * Rjz;
        const float sjy = i10 * Rjx + i11 * Rjy + i12 * Rjz;
        const float sjz = i20 * Rjx + i21 * Rjy + i22 * Rjz;
        // minimum image in fractional space (jnp.round == rint)
        float dsx = six - sjx; dsx -= rintf(dsx);
        float dsy = siy - sjy; dsy -= rintf(dsy);
        float dsz = siz - sjz; dsz -= rintf(dsz);
        const float dx = b00 * dsx + b01 * dsy + b02 * dsz;
        const float dy = b10 * dsx + b11 * dsy + b12 * dsz;
        const float dz = b20 * dsx + b21 * dsy + b22 * dsz;
        const float r2 = dx * dx + dy * dy + dz * dz;
        const float r  = sqrtf(r2);
        if (r >= RC_) continue;   // fc == 0 beyond cutoff

        const float fc = 0.5f * (__cosf(PI_F * (r * (1.0f / RC_))) + 1.0f);

        // radial: q_r[k] += r^k * fc   (qr[0..2] are also the S moments)
        float rp = 1.0f;
#pragma unroll
        for (int k = 0; k < 9; ++k) { qr[k] += rp * fc; rp *= r; }

        // angular moments with w_n = fc * r^n, unit vector u
        const float ir = 1.0f / r;
        const float ux = dx * ir, uy = dy * ir, uz = dz * ir;
        float w = fc;
#pragma unroll
        for (int n = 0; n < 3; ++n) {
            V[n][0] += w * ux;      V[n][1] += w * uy;      V[n][2] += w * uz;
            M[n][0] += w * ux * ux; M[n][1] += w * uy * uy; M[n][2] += w * uz * uz;
            M[n][3] += w * ux * uy; M[n][4] += w * ux * uz; M[n][5] += w * uy * uz;
            w *= r;
        }
    }

    // ---- wave-wide butterfly reduction over 64 lanes (36 floats) ----
#pragma unroll
    for (int off = 32; off > 0; off >>= 1) {
#pragma unroll
        for (int k = 0; k < 9; ++k) qr[k] += __shfl_xor(qr[k], off);
#pragma unroll
        for (int n = 0; n < 3; ++n) {
#pragma unroll
            for (int c = 0; c < 3; ++c) V[n][c] += __shfl_xor(V[n][c], off);
#pragma unroll
            for (int c = 0; c < 6; ++c) M[n][c] += __shfl_xor(M[n][c], off);
        }
    }

    if (lane == 0) {
        float* o = out + i * 18;
#pragma unroll
        for (int k = 0; k < 9; ++k) o[k] = qr[k];
#pragma unroll
        for (int n = 0; n < 3; ++n) {
            const float s  = qr[n];   // S[n] == q_r[n]
            const float v2 = V[n][0] * V[n][0] + V[n][1] * V[n][1] + V[n][2] * V[n][2];
            const float m2 = M[n][0] * M[n][0] + M[n][1] * M[n][1] + M[n][2] * M[n][2]
                     + 2.0f * (M[n][3] * M[n][3] + M[n][4] * M[n][4] + M[n][5] * M[n][5]);
            o[9 + n * 3 + 0] = s * s;                    // P0
            o[9 + n * 3 + 1] = v2;                       // P1
            o[9 + n * 3 + 2] = 1.5f * m2 - 0.5f * s * s; // P2
        }
    }
}

} // namespace

extern "C" void kernel_launch(void* const* d_in, const int* in_sizes, int n_in,
                              void* d_out, int out_size, void* d_ws, size_t ws_size,
                              hipStream_t stream)
{
    const float* R   = (const float*)d_in[0];   // [N,3] float32
    // d_in[1] = Z (int32) — unused by the reference computation
    const float* box = (const float*)d_in[2];   // [3,3] float32
    float* out = (float*)d_out;                 // [N,18] float32
    const int N = in_sizes[0] / 3;

    desc_kernel<<<dim3(N), dim3(64), 0, stream>>>(R, box, out, N);
}